// Round 1
// baseline (404.916 us; speedup 1.0000x reference)
//
#include <hip/hip_runtime.h>
#include <math.h>

typedef unsigned short u16;
typedef __attribute__((ext_vector_type(4))) float f32x4;
typedef __attribute__((ext_vector_type(8))) short s16x8;

__device__ __forceinline__ u16 f2bf(float f){
  unsigned u = __builtin_bit_cast(unsigned, f);
  u += 0x7fffu + ((u >> 16) & 1u);
  return (u16)(u >> 16);
}
__device__ __forceinline__ float bf2f(u16 h){
  unsigned u = ((unsigned)h) << 16;
  return __builtin_bit_cast(float, u);
}
__device__ __forceinline__ f32x4 mfma16(s16x8 a, s16x8 b, f32x4 c){
  return __builtin_amdgcn_mfma_f32_16x16x32_bf16(a, b, c, 0, 0, 0);
}

// ---------------- split x -> bf16 hi/lo ----------------
__global__ __launch_bounds__(256) void k_split(const float* __restrict__ x,
    u16* __restrict__ xh, u16* __restrict__ xl, int n4){
  int id = blockIdx.x*256 + threadIdx.x;
  if (id >= n4) return;
  float4 v = ((const float4*)x)[id];
  float vv[4] = {v.x, v.y, v.z, v.w};
  u16 hh[4], ll[4];
  #pragma unroll
  for (int i=0;i<4;++i){ hh[i] = f2bf(vv[i]); ll[i] = f2bf(vv[i] - bf2f(hh[i])); }
  ((ushort4*)xh)[id] = make_ushort4(hh[0],hh[1],hh[2],hh[3]);
  ((ushort4*)xl)[id] = make_ushort4(ll[0],ll[1],ll[2],ll[3]);
}

// ------------- transpose + split: in[R][C] f32 -> out[C][R] bf16 hi/lo -------------
__global__ __launch_bounds__(256) void k_tsplit(const float* __restrict__ in,
    u16* __restrict__ oh, u16* __restrict__ ol, int R, int C){
  __shared__ float tile[32][33];
  int tx = threadIdx.x & 31, ty = threadIdx.x >> 5;
  int c0 = blockIdx.x*32, r0 = blockIdx.y*32;
  #pragma unroll
  for (int rr=0; rr<4; ++rr){
    int row = ty*4 + rr;
    tile[row][tx] = in[(size_t)(r0+row)*C + (c0+tx)];
  }
  __syncthreads();
  #pragma unroll
  for (int rr=0; rr<4; ++rr){
    int row = ty*4 + rr;
    float v = tile[tx][row];
    size_t o = (size_t)(c0+row)*R + (r0+tx);
    u16 hh = f2bf(v);
    oh[o] = hh; ol[o] = f2bf(v - bf2f(hh));
  }
}

// ------------- split-bf16 GEMM: C[M][N] = A[M][K] * B[N][K]^T (3-term compensated) -------------
__global__ __launch_bounds__(256) void k_gemm(const u16* __restrict__ Ah, const u16* __restrict__ Al,
    const u16* __restrict__ Bh, const u16* __restrict__ Bl, float* __restrict__ C,
    int M, int N, int K){
  __shared__ u16 As[2][128][72];
  __shared__ u16 Bs[2][64][72];
  int t = threadIdx.x;
  int n0 = blockIdx.x*64, m0 = blockIdx.y*128;
  int w = t>>6, lane = t&63, lg = lane>>4, lr = lane&15;
  int iw = w&1, jw = w>>1;
  f32x4 acc[4][2] = {};
  for (int k0=0; k0<K; k0+=64){
    __syncthreads();
    #pragma unroll
    for (int it=0; it<4; ++it){
      int id = it*256+t; int row=id>>3, c8=id&7;
      *(uint4*)&As[0][row][c8*8] = *(const uint4*)(Ah + (size_t)(m0+row)*K + k0 + c8*8);
      *(uint4*)&As[1][row][c8*8] = *(const uint4*)(Al + (size_t)(m0+row)*K + k0 + c8*8);
    }
    #pragma unroll
    for (int it=0; it<2; ++it){
      int id = it*256+t; int row=id>>3, c8=id&7;
      *(uint4*)&Bs[0][row][c8*8] = *(const uint4*)(Bh + (size_t)(n0+row)*K + k0 + c8*8);
      *(uint4*)&Bs[1][row][c8*8] = *(const uint4*)(Bl + (size_t)(n0+row)*K + k0 + c8*8);
    }
    __syncthreads();
    #pragma unroll
    for (int ks=0; ks<2; ++ks){
      int kk = ks*32 + lg*8;
      s16x8 ah[4], al[4], bh[2], bl[2];
      #pragma unroll
      for (int m=0;m<4;++m){
        int r = iw*64 + m*16 + lr;
        ah[m] = *(const s16x8*)&As[0][r][kk];
        al[m] = *(const s16x8*)&As[1][r][kk];
      }
      #pragma unroll
      for (int nn=0;nn<2;++nn){
        int r = jw*32 + nn*16 + lr;
        bh[nn] = *(const s16x8*)&Bs[0][r][kk];
        bl[nn] = *(const s16x8*)&Bs[1][r][kk];
      }
      #pragma unroll
      for (int m=0;m<4;++m)
        #pragma unroll
        for(int nn=0;nn<2;++nn){
          acc[m][nn] = mfma16(ah[m], bh[nn], acc[m][nn]);
          acc[m][nn] = mfma16(ah[m], bl[nn], acc[m][nn]);
          acc[m][nn] = mfma16(al[m], bh[nn], acc[m][nn]);
        }
    }
  }
  #pragma unroll
  for (int m=0;m<4;++m)
    #pragma unroll
    for(int nn=0;nn<2;++nn)
      #pragma unroll
      for(int r=0;r<4;++r){
        int row = m0 + iw*64 + m*16 + lg*4 + r;
        int col = n0 + jw*32 + nn*16 + lr;
        C[(size_t)row*N + col] = acc[m][nn][r];
      }
}

// ------------- rmsnorm + rope + split/transposed layouts -------------
__device__ __forceinline__ float blocksum128(float v, float* red, int t){
  #pragma unroll
  for (int m=32; m>=1; m>>=1) v += __shfl_xor(v, m, 64);
  __syncthreads();
  if ((t&63)==0) red[t>>6] = v;
  __syncthreads();
  return red[0] + red[1];
}

__global__ __launch_bounds__(128) void k_normrope(const float* __restrict__ qkv,
   const float* __restrict__ rot, const float* __restrict__ qw, const float* __restrict__ kw,
   const float* __restrict__ vw, u16* __restrict__ Qh, u16* __restrict__ Ql,
   u16* __restrict__ Kh, u16* __restrict__ Kl, u16* __restrict__ Vt){
  __shared__ float buf[128];
  __shared__ float red[2];
  int n = blockIdx.x, t = threadIdx.x;
  const float* row = qkv + (size_t)n*1344;
  float pos = rot[(size_t)n*128 + t];
  float cs = cosf(pos), sn = sinf(pos);
  float qwt = qw[t], kwt = kw[t];
  #pragma unroll 1
  for (int h=0; h<8; ++h){
    float v = row[h*128 + t];
    float ss = blocksum128(v*v, red, t);
    float rr = rsqrtf(ss*(1.0f/128.0f) + 1.1920929e-07f);
    float qn = v*rr*qwt*0.125f;
    __syncthreads();
    buf[t] = qn;
    __syncthreads();
    float partner = (t<64) ? -buf[t+64] : buf[t-64];
    float o = qn*cs + partner*sn;
    u16 hh = f2bf(o);
    size_t oi = ((size_t)h*2048 + n)*128 + t;
    Qh[oi] = hh; Ql[oi] = f2bf(o - bf2f(hh));
  }
  {
    float v = row[1024 + t];
    float ss = blocksum128(v*v, red, t);
    float rr = rsqrtf(ss*(1.0f/128.0f) + 1.1920929e-07f);
    float kn = v*rr*kwt;
    __syncthreads();
    buf[t] = kn;
    __syncthreads();
    float partner = (t<64) ? -buf[t+64] : buf[t-64];
    float o = kn*cs + partner*sn;
    u16 hh = f2bf(o);
    size_t oi = (size_t)n*128 + t;
    Kh[oi] = hh; Kl[oi] = f2bf(o - bf2f(hh));
  }
  {
    float v0 = row[1152 + t];
    float v1 = (t<64) ? row[1280 + t] : 0.0f;
    float ss = blocksum128(v0*v0 + v1*v1, red, t);
    float rr = rsqrtf(ss*(1.0f/192.0f) + 1.1920929e-07f);
    Vt[(size_t)t*2048 + n] = f2bf(v0*rr*vw[t]);
    if (t < 64) Vt[(size_t)(128+t)*2048 + n] = f2bf(v1*rr*vw[128+t]);
  }
}

// ------------- pairwise -> attention bias: bias[h][i][j] -------------
__global__ __launch_bounds__(256) void k_bias(const float* __restrict__ pw, const float* __restrict__ rv,
  const float* __restrict__ gamma, const float* __restrict__ beta, const float* __restrict__ Wb,
  float* __restrict__ bias){
  int t = threadIdx.x;
  int g = t & 31, sub = t >> 5;
  size_t pair = (size_t)blockIdx.x*8 + sub;
  int c = g*4;
  const float4 x4  = *(const float4*)(pw + pair*128 + c);
  const float4 rv4 = *(const float4*)(rv + c);
  const float4 g4  = *(const float4*)(gamma + c);
  const float4 b4  = *(const float4*)(beta + c);
  float xs[4] = {x4.x, x4.y, x4.z, x4.w};
  float rvs[4] = {rv4.x, rv4.y, rv4.z, rv4.w};
  float gs[4] = {g4.x, g4.y, g4.z, g4.w};
  float bs[4] = {b4.x, b4.y, b4.z, b4.w};
  float p[8] = {0,0,0,0,0,0,0,0};
  #pragma unroll
  for (int kk=0; kk<4; ++kk){
    float xv = xs[kk] * (11.313708498984761f * rsqrtf(fmaxf(rvs[kk], 1e-5f))) * (gs[kk] + 1.0f) + bs[kk];
    float ge = 0.5f * xv * (1.0f + erff(xv * 0.7071067811865476f));
    #pragma unroll
    for (int hh=0; hh<8; ++hh) p[hh] += ge * Wb[(c+kk)*8 + hh];
  }
  #pragma unroll
  for (int m=1; m<32; m<<=1){
    #pragma unroll
    for (int hh=0; hh<8; ++hh) p[hh] += __shfl_xor(p[hh], m, 64);
  }
  if (g < 8) bias[(size_t)g*(512*512) + pair] = p[g];
}

// ------------- fused attention: QK^T(split) + bias + softcap + softmax + PV -------------
__global__ __launch_bounds__(256) void k_attn(const u16* __restrict__ Qh, const u16* __restrict__ Ql,
  const u16* __restrict__ Kh, const u16* __restrict__ Kl, const u16* __restrict__ Vt,
  const float* __restrict__ bias, u16* __restrict__ Oh, u16* __restrict__ Ol){
  __shared__ u16 KhS[32][136];
  __shared__ u16 KlS[32][136];
  __shared__ u16 VtS[192][40];
  __shared__ u16 PS[32][40];
  __shared__ float lsum[32][2];
  int t = threadIdx.x;
  int h = blockIdx.y;
  int q0 = blockIdx.x * 32;
  int w = t>>6, lane = t&63, lg = lane>>4, lr = lane&15;
  int iw = w&1, jw = w>>1;
  s16x8 qfh[4], qfl[4];
  {
    int row = q0 + iw*16 + lr;
    const u16* qb  = Qh + ((size_t)h*2048 + row)*128;
    const u16* qb2 = Ql + ((size_t)h*2048 + row)*128;
    #pragma unroll
    for (int ks=0; ks<4; ++ks){
      qfh[ks] = *(const s16x8*)(qb  + ks*32 + lg*8);
      qfl[ks] = *(const s16x8*)(qb2 + ks*32 + lg*8);
    }
  }
  f32x4 accO[6] = {};
  float psum[4] = {0,0,0,0};
  const float* biasH = bias + (size_t)h*512*512;
  for (int jt=0; jt<64; ++jt){
    int j0 = jt*32;
    __syncthreads();
    #pragma unroll
    for (int it=0; it<2; ++it){
      int id = it*256 + t, rrow = id>>4, c8 = id&15;
      *(uint4*)&KhS[rrow][c8*8] = *(const uint4*)(Kh + (size_t)(j0+rrow)*128 + c8*8);
      *(uint4*)&KlS[rrow][c8*8] = *(const uint4*)(Kl + (size_t)(j0+rrow)*128 + c8*8);
    }
    #pragma unroll
    for (int it=0; it<3; ++it){
      int id = it*256 + t, rrow = id>>2, c8 = id&3;
      *(uint4*)&VtS[rrow][c8*8] = *(const uint4*)(Vt + (size_t)rrow*2048 + j0 + c8*8);
    }
    __syncthreads();
    f32x4 accS = {0.f,0.f,0.f,0.f};
    #pragma unroll
    for (int ks=0; ks<4; ++ks){
      int kk = ks*32 + lg*8;
      s16x8 kbh = *(const s16x8*)&KhS[jw*16 + lr][kk];
      s16x8 kbl = *(const s16x8*)&KlS[jw*16 + lr][kk];
      accS = mfma16(qfh[ks], kbh, accS);
      accS = mfma16(qfh[ks], kbl, accS);
      accS = mfma16(qfl[ks], kbh, accS);
    }
    #pragma unroll
    for (int r=0; r<4; ++r){
      int gi = q0 + iw*16 + lg*4 + r;
      int gj = j0 + jw*16 + lr;
      float s = accS[r] + biasH[(size_t)(gi>>2)*512 + (gj>>2)];
      float cap = 5.0f * tanhf(s * 0.2f);
      float p = expf(cap);
      psum[r] += p;
      PS[iw*16 + lg*4 + r][jw*16 + lr] = f2bf(p);
    }
    __syncthreads();
    {
      s16x8 pa = *(const s16x8*)&PS[iw*16 + lr][lg*8];
      #pragma unroll
      for (int df=0; df<6; ++df){
        s16x8 vb = *(const s16x8*)&VtS[jw*96 + df*16 + lr][lg*8];
        accO[df] = mfma16(pa, vb, accO[df]);
      }
    }
  }
  #pragma unroll
  for (int m=1; m<16; m<<=1){
    #pragma unroll
    for (int r=0; r<4; ++r) psum[r] += __shfl_xor(psum[r], m, 64);
  }
  if (lr == 0){
    #pragma unroll
    for (int r=0; r<4; ++r) lsum[iw*16 + lg*4 + r][jw] = psum[r];
  }
  __syncthreads();
  float inv[4];
  #pragma unroll
  for (int r=0; r<4; ++r){
    int rloc = iw*16 + lg*4 + r;
    inv[r] = 1.0f / (lsum[rloc][0] + lsum[rloc][1]);
  }
  #pragma unroll
  for (int df=0; df<6; ++df){
    #pragma unroll
    for (int r=0; r<4; ++r){
      float o = accO[df][r] * inv[r];
      int rrow = q0 + iw*16 + lg*4 + r;
      int col = h*192 + jw*96 + df*16 + lr;
      u16 hh = f2bf(o);
      size_t oi = (size_t)rrow*1536 + col;
      Oh[oi] = hh; Ol[oi] = f2bf(o - bf2f(hh));
    }
  }
}

extern "C" void kernel_launch(void* const* d_in, const int* in_sizes, int n_in,
                              void* d_out, int out_size, void* d_ws, size_t ws_size,
                              hipStream_t stream){
  (void)in_sizes; (void)n_in; (void)out_size; (void)ws_size;
  const float* x   = (const float*)d_in[0];
  const float* pwi = (const float*)d_in[1];
  const float* rot = (const float*)d_in[2];
  const float* Wq  = (const float*)d_in[3];
  const float* qw  = (const float*)d_in[4];
  const float* kw  = (const float*)d_in[5];
  const float* vw  = (const float*)d_in[6];
  const float* gm  = (const float*)d_in[7];
  const float* bt  = (const float*)d_in[8];
  const float* rvv = (const float*)d_in[9];
  const float* Wb  = (const float*)d_in[10];
  const float* Wo  = (const float*)d_in[11];
  float* out = (float*)d_out;
  char* ws = (char*)d_ws;
  size_t off = 0;
  auto alloc = [&](size_t bytes)->char*{
    char* p = ws + off; off = (off + bytes + 255) & ~(size_t)255; return p;
  };
  u16* xh  = (u16*)alloc(2048ull*1024*2);
  u16* xl  = (u16*)alloc(2048ull*1024*2);
  u16* Wqh = (u16*)alloc(1344ull*1024*2);
  u16* Wql = (u16*)alloc(1344ull*1024*2);
  u16* Woh = (u16*)alloc(1024ull*1536*2);
  u16* Wol = (u16*)alloc(1024ull*1536*2);
  float* qkv = (float*)alloc(2048ull*1344*4);
  u16* Qhb = (u16*)alloc(8ull*2048*128*2);
  u16* Qlb = (u16*)alloc(8ull*2048*128*2);
  u16* Khb = (u16*)alloc(2048ull*128*2);
  u16* Klb = (u16*)alloc(2048ull*128*2);
  u16* Vtb = (u16*)alloc(192ull*2048*2);
  float* bias = (float*)alloc(8ull*512*512*4);
  u16* Ohb = (u16*)alloc(2048ull*1536*2);
  u16* Olb = (u16*)alloc(2048ull*1536*2);

  k_split<<<2048, 256, 0, stream>>>(x, xh, xl, 524288);
  k_tsplit<<<dim3(1344/32, 1024/32), 256, 0, stream>>>(Wq, Wqh, Wql, 1024, 1344);
  k_tsplit<<<dim3(1024/32, 1536/32), 256, 0, stream>>>(Wo, Woh, Wol, 1536, 1024);
  k_gemm<<<dim3(1344/64, 2048/128), 256, 0, stream>>>(xh, xl, Wqh, Wql, qkv, 2048, 1344, 1024);
  k_normrope<<<2048, 128, 0, stream>>>(qkv, rot, qw, kw, vw, Qhb, Qlb, Khb, Klb, Vtb);
  k_bias<<<512*512/8, 256, 0, stream>>>(pwi, rvv, gm, bt, Wb, bias);
  k_attn<<<dim3(2048/32, 8), 256, 0, stream>>>(Qhb, Qlb, Khb, Klb, Vtb, bias, Ohb, Olb);
  k_gemm<<<dim3(1024/64, 2048/128), 256, 0, stream>>>(Ohb, Olb, Woh, Wol, out, 2048, 1024, 1536);
}